// Round 2
// baseline (367.605 us; speedup 1.0000x reference)
//
#include <hip/hip_runtime.h>

#define LW 16
#define CLASSNUM 1000
#define DIM (CLASSNUM * LW)   // 16000 floats per row
#define NROWS 4096
#define BLK 256
#define QPR 4                 // quarter-row blocks per row
#define F4_PER_Q 1000         // float4 elements per quarter (4000/4)

// 16384 blocks: block b handles quarter (b&3) of row (b>>2).
// Each thread loads at most 4 float4 (3 unconditional + 1 masked remainder),
// block-reduces sum(x^2) and writes one partial per block — no atomics.
__global__ __launch_bounds__(BLK) void rvs_sq_kernel(
    const float* __restrict__ inputs,
    float* __restrict__ ws) {
    const int b = blockIdx.x;
    const int row = b >> 2;
    const int q = b & 3;
    const int tid = threadIdx.x;
    const float4* p = (const float4*)inputs + (size_t)row * (DIM / 4) + q * F4_PER_Q;

    float s = 0.0f;
    #pragma unroll
    for (int k = 0; k < 3; ++k) {
        float4 v = p[k * BLK + tid];
        s += v.x * v.x + v.y * v.y + v.z * v.z + v.w * v.w;
    }
    {
        int idx = 3 * BLK + tid;          // 768..1023, valid while < 1000
        if (idx < F4_PER_Q) {
            float4 v = p[idx];
            s += v.x * v.x + v.y * v.y + v.z * v.z + v.w * v.w;
        }
    }

    #pragma unroll
    for (int off = 32; off > 0; off >>= 1)
        s += __shfl_down(s, off, 64);

    __shared__ float l[BLK / 64];
    if ((tid & 63) == 0) l[tid >> 6] = s;
    __syncthreads();
    if (tid == 0) ws[b] = l[0] + l[1] + l[2] + l[3];
}

// Single-block epilogue: per row, sq = sum of its 4 partials; add the
// gathered/weighted linear term; reduce everything to out[0]/N.
__global__ __launch_bounds__(BLK) void rvs_tail_kernel(
    const float* __restrict__ inputs,
    const float* __restrict__ labels,
    const float* __restrict__ ws,
    float* __restrict__ out) {
    const int tid = threadIdx.x;
    float acc = 0.0f;

    for (int r = tid; r < NROWS; r += BLK) {
        float sq = ws[4 * r] + ws[4 * r + 1] + ws[4 * r + 2] + ws[4 * r + 3];
        const float* lab = labels + r * (LW + 1);
        const int c = (int)lab[LW];
        const float* g = inputs + (size_t)r * DIM + c * LW;
        float wsum = 0.0f, lin = 0.0f;
        #pragma unroll
        for (int j = 0; j < LW; ++j) {
            float wj = lab[j];
            wsum += wj;
            lin += wj * (1.0f - 2.0f * g[j]);
        }
        acc += sq * wsum + lin;
    }

    #pragma unroll
    for (int off = 32; off > 0; off >>= 1)
        acc += __shfl_down(acc, off, 64);

    __shared__ float l[BLK / 64];
    if ((tid & 63) == 0) l[tid >> 6] = acc;
    __syncthreads();
    if (tid == 0) out[0] = (l[0] + l[1] + l[2] + l[3]) / (float)NROWS;
}

extern "C" void kernel_launch(void* const* d_in, const int* in_sizes, int n_in,
                              void* d_out, int out_size, void* d_ws, size_t ws_size,
                              hipStream_t stream) {
    const float* inputs = (const float*)d_in[0];   // (4096, 16000) f32
    const float* labels = (const float*)d_in[1];   // (4096, 17)    f32
    float* out = (float*)d_out;                    // (1,) f32
    float* ws = (float*)d_ws;                      // >= 16384 floats

    rvs_sq_kernel<<<NROWS * QPR, BLK, 0, stream>>>(inputs, ws);
    rvs_tail_kernel<<<1, BLK, 0, stream>>>(inputs, labels, ws, out);
}